// Round 1
// baseline (7463.737 us; speedup 1.0000x reference)
//
#include <hip/hip_runtime.h>
#include <cstdint>

// NystromAttention, B=4, S=1024, D=768, m=S (identity pooling).
// out = Qp * h(G) * M,  G = Kp^T Kp,  M = Kp^T (Kp*Vp),
// h(lam) = (1/lam) * 1[lam >= tau],  tau = 0.001220703125 * lamMax  (jax pinv default rtol)
// h(G) built GEMM-only: Newton-Schulz sign(G - tau I) -> projector -> seeded Newton inverse.
// Workspace: 3*B*S*D + 3*B*D*D + 16 floats = 63.0 MiB.

#define NB 4
#define SS 1024
#define DD 768

static const long PB = (long)SS * DD;       // per-batch [S,D] stride
static const long GB = (long)DD * DD;       // per-batch [D,D] stride
static const long SZ_P = (long)NB * PB;
static const long SZ_G = (long)NB * GB;

// ---------------------------------------------------------------------------
// Generic fp32 GEMM: C = alpha*(A[M,K]*Bm[K,N]) + beta*D + bias (row-broadcast)
// Row-major, batched over blockIdx.z with per-operand strides (0 = shared).
// Tile 64x64, BK=16, 256 threads, 4x4 per thread.
// ---------------------------------------------------------------------------
__global__ __launch_bounds__(256)
void gemm_f32(int M, int N, int K,
              const float* __restrict__ A, long sA,
              const float* __restrict__ Bm, long sB,
              float* __restrict__ C, long sC,
              const float* __restrict__ Dm, long sD,
              const float* __restrict__ bias,
              float alpha, float beta)
{
    const int b = blockIdx.z;
    const float* Ab = A + (long)b * sA;
    const float* Bb = Bm + (long)b * sB;
    float*       Cb = C + (long)b * sC;
    const float* Db = Dm ? (Dm + (long)b * sD) : nullptr;

    __shared__ float As[16][68];   // A-tile transposed: As[k][row]; +4 pad (16B-aligned rows)
    __shared__ float Bs[16][68];   // B-tile: Bs[k][col]

    const int tid = threadIdx.x;
    const int tx = tid & 15, ty = tid >> 4;
    const int row0 = blockIdx.y * 64, col0 = blockIdx.x * 64;

    const int lar = tid >> 2;          // A load: row in tile
    const int lak = (tid & 3) << 2;    // A load: k0 offset (float4)
    const int lbc = (tid & 15) << 2;   // B load: col (float4)
    const int lbk = tid >> 4;          // B load: k

    float acc[4][4] = {};

    for (int k0 = 0; k0 < K; k0 += 16) {
        float4 av = *(const float4*)(Ab + (long)(row0 + lar) * K + (k0 + lak));
        float4 bv = *(const float4*)(Bb + (long)(k0 + lbk) * N + (col0 + lbc));
        As[lak + 0][lar] = av.x;
        As[lak + 1][lar] = av.y;
        As[lak + 2][lar] = av.z;
        As[lak + 3][lar] = av.w;
        *(float4*)(&Bs[lbk][lbc]) = bv;
        __syncthreads();
#pragma unroll
        for (int kk = 0; kk < 16; ++kk) {
            float4 a4 = *(const float4*)(&As[kk][ty << 2]);
            float4 b4 = *(const float4*)(&Bs[kk][tx << 2]);
            float ar[4] = {a4.x, a4.y, a4.z, a4.w};
            float br[4] = {b4.x, b4.y, b4.z, b4.w};
#pragma unroll
            for (int i = 0; i < 4; ++i)
#pragma unroll
                for (int j = 0; j < 4; ++j)
                    acc[i][j] = fmaf(ar[i], br[j], acc[i][j]);
        }
        __syncthreads();
    }

#pragma unroll
    for (int i = 0; i < 4; ++i) {
        const int r = row0 + (ty << 2) + i;
#pragma unroll
        for (int j = 0; j < 4; ++j) {
            const int c = col0 + (tx << 2) + j;
            float vv = alpha * acc[i][j];
            if (Db)   vv += beta * Db[(long)r * N + c];
            if (bias) vv += bias[c];
            Cb[(long)r * N + c] = vv;
        }
    }
}

// ---------------------------------------------------------------------------
// Fused Gram: G = Kp^T Kp, Mo = Kp^T (Kp*Vp).  Output 768x768, K-dim = 1024.
// ---------------------------------------------------------------------------
__global__ __launch_bounds__(256)
void gram_gm(const float* __restrict__ KP, const float* __restrict__ VP,
             float* __restrict__ G, float* __restrict__ Mo)
{
    const int b = blockIdx.z;
    const float* Kb = KP + (long)b * PB;
    const float* Vb = VP + (long)b * PB;
    float* Gb = G  + (long)b * GB;
    float* Mb = Mo + (long)b * GB;

    __shared__ float As[16][68];   // Kp[s, i-tile]
    __shared__ float Bs[16][68];   // Kp[s, j-tile]
    __shared__ float Cs[16][68];   // (Kp*Vp)[s, j-tile]

    const int tid = threadIdx.x;
    const int tx = tid & 15, ty = tid >> 4;
    const int i0 = blockIdx.y * 64, j0 = blockIdx.x * 64;
    const int lc = (tid & 15) << 2;
    const int ls = tid >> 4;

    float accG[4][4] = {};
    float accM[4][4] = {};

    for (int s0 = 0; s0 < SS; s0 += 16) {
        const long ro = (long)(s0 + ls) * DD;
        float4 ka = *(const float4*)(Kb + ro + i0 + lc);
        float4 kb = *(const float4*)(Kb + ro + j0 + lc);
        float4 vb = *(const float4*)(Vb + ro + j0 + lc);
        *(float4*)(&As[ls][lc]) = ka;
        *(float4*)(&Bs[ls][lc]) = kb;
        float4 kv = make_float4(kb.x * vb.x, kb.y * vb.y, kb.z * vb.z, kb.w * vb.w);
        *(float4*)(&Cs[ls][lc]) = kv;
        __syncthreads();
#pragma unroll
        for (int ss = 0; ss < 16; ++ss) {
            float4 a4 = *(const float4*)(&As[ss][ty << 2]);
            float4 b4 = *(const float4*)(&Bs[ss][tx << 2]);
            float4 c4 = *(const float4*)(&Cs[ss][tx << 2]);
            float ar[4] = {a4.x, a4.y, a4.z, a4.w};
            float br[4] = {b4.x, b4.y, b4.z, b4.w};
            float cr[4] = {c4.x, c4.y, c4.z, c4.w};
#pragma unroll
            for (int i = 0; i < 4; ++i)
#pragma unroll
                for (int j = 0; j < 4; ++j) {
                    accG[i][j] = fmaf(ar[i], br[j], accG[i][j]);
                    accM[i][j] = fmaf(ar[i], cr[j], accM[i][j]);
                }
        }
        __syncthreads();
    }

#pragma unroll
    for (int i = 0; i < 4; ++i) {
        const int r = i0 + (ty << 2) + i;
#pragma unroll
        for (int j = 0; j < 4; ++j) {
            const int c = j0 + (tx << 2) + j;
            Gb[(long)r * DD + c] = accG[i][j];
            Mb[(long)r * DD + c] = accM[i][j];
        }
    }
}

// ---------------------------------------------------------------------------
// Row softmax over D=768 (matches jax.nn.softmax: sub-max, exp, divide).
// One wave per row, 4 waves per block.
// ---------------------------------------------------------------------------
__global__ __launch_bounds__(256)
void softmax_rows(float* __restrict__ P)
{
    const int row  = blockIdx.x * 4 + (threadIdx.x >> 6);
    const int lane = threadIdx.x & 63;
    float* rp = P + (long)row * DD;
    float v[12];
    float mx = -3.4e38f;
#pragma unroll
    for (int i = 0; i < 12; ++i) { v[i] = rp[lane + (i << 6)]; mx = fmaxf(mx, v[i]); }
#pragma unroll
    for (int off = 32; off > 0; off >>= 1) mx = fmaxf(mx, __shfl_xor(mx, off, 64));
    float sum = 0.f;
#pragma unroll
    for (int i = 0; i < 12; ++i) { v[i] = expf(v[i] - mx); sum += v[i]; }
#pragma unroll
    for (int off = 32; off > 0; off >>= 1) sum += __shfl_xor(sum, off, 64);
#pragma unroll
    for (int i = 0; i < 12; ++i) rp[lane + (i << 6)] = v[i] / sum;
}

// ---------------------------------------------------------------------------
// Power iteration for lamMax(G) per batch; writes scal = {lam[4], tau[4], invlam[4]}.
// Gap lam1/lam2 ~ 130 => converges in ~3 iters; run 12.
// ---------------------------------------------------------------------------
__global__ __launch_bounds__(256)
void power_iter(const float* __restrict__ G, float* __restrict__ scal)
{
    const int b = blockIdx.x;
    const float* Gb = G + (long)b * GB;
    __shared__ __align__(16) float v[DD];
    __shared__ float w[DD];
    __shared__ float red[256];
    const int t = threadIdx.x;
    for (int i = t; i < DD; i += 256) v[i] = 1.0f;   // G > 0 elementwise => Perron start
    __syncthreads();
    float lam = 1.f;
    for (int it = 0; it < 12; ++it) {
        for (int r = t; r < DD; r += 256) {
            const float4* gr = (const float4*)(Gb + (long)r * DD);
            float s = 0.f;
            for (int c4 = 0; c4 < DD / 4; ++c4) {
                float4 g4 = gr[c4];
                float4 vv = *(const float4*)(&v[c4 << 2]);
                s = fmaf(g4.x, vv.x, s); s = fmaf(g4.y, vv.y, s);
                s = fmaf(g4.z, vv.z, s); s = fmaf(g4.w, vv.w, s);
            }
            w[r] = s;
        }
        __syncthreads();
        float ps = 0.f;
        for (int i = t; i < DD; i += 256) ps += w[i] * w[i];
        red[t] = ps; __syncthreads();
        for (int off = 128; off > 0; off >>= 1) {
            if (t < off) red[t] += red[t + off];
            __syncthreads();
        }
        lam = sqrtf(red[0]);          // ||G v|| for unit v -> lamMax at convergence
        const float inv = 1.0f / lam;
        __syncthreads();
        for (int i = t; i < DD; i += 256) v[i] = w[i] * inv;
        __syncthreads();
    }
    if (t == 0) {
        scal[b]     = lam;
        scal[4 + b] = 1.220703125e-3f * lam;   // jax pinv: rtol = 10*1024*eps (exact)
        scal[8 + b] = 1.0f / lam;
    }
}

// X = (G - tau*I) / lamMax   (spectrum in [-1,1])
__global__ __launch_bounds__(256)
void mat_sign_init(const float* __restrict__ G, float* __restrict__ X,
                   const float* __restrict__ scal)
{
    const long idx = (long)blockIdx.x * 256 + threadIdx.x;
    if (idx >= SZ_G) return;
    const int b = (int)(idx / GB);
    const long rem = idx % GB;
    const int r = (int)(rem / DD), c = (int)(rem % DD);
    float g = G[idx];
    if (r == c) g -= scal[4 + b];
    X[idx] = g * scal[8 + b];
}

// X0 = (S + I) * (0.5 / lamMax)   (seeded Newton-inverse start = P/lamMax)
__global__ __launch_bounds__(256)
void mat_proj_init(const float* __restrict__ Sg, float* __restrict__ X,
                   const float* __restrict__ scal)
{
    const long idx = (long)blockIdx.x * 256 + threadIdx.x;
    if (idx >= SZ_G) return;
    const int b = (int)(idx / GB);
    const long rem = idx % GB;
    const int r = (int)(rem / DD), c = (int)(rem % DD);
    float s = Sg[idx];
    if (r == c) s += 1.0f;
    X[idx] = s * 0.5f * scal[8 + b];
}

// ---------------------------------------------------------------------------
extern "C" void kernel_launch(void* const* d_in, const int* in_sizes, int n_in,
                              void* d_out, int out_size, void* d_ws, size_t ws_size,
                              hipStream_t stream)
{
    (void)in_sizes; (void)n_in; (void)out_size; (void)ws_size;
    const float* q  = (const float*)d_in[0];
    const float* k  = (const float*)d_in[1];
    const float* v  = (const float*)d_in[2];
    const float* Wq = (const float*)d_in[3];
    const float* bq = (const float*)d_in[4];
    const float* Wk = (const float*)d_in[5];
    const float* bk = (const float*)d_in[6];
    const float* Wv = (const float*)d_in[7];
    const float* bv = (const float*)d_in[8];
    float* out = (float*)d_out;

    float* ws = (float*)d_ws;
    float* QP   = ws;                 // [B,S,D]   live to the end
    float* KP   = QP + SZ_P;          // [B,S,D]   dead after gram  -> reused as X
    float* VP   = KP + SZ_P;          // [B,S,D]   dead after gram  -> reused as T2
    float* G    = VP + SZ_P;          // [B,D,D]
    float* Mm   = G  + SZ_G;          // [B,D,D]
    float* T1   = Mm + SZ_G;          // [B,D,D]
    float* scal = T1 + SZ_G;          // 12 floats
    float* X  = KP;
    float* T2 = VP;

    const dim3 blk(256);
    const dim3 gP(DD / 64, SS / 64, NB);   // [S,D] outputs
    const dim3 gG(DD / 64, DD / 64, NB);   // [D,D] outputs
    const dim3 gE((unsigned)((SZ_G + 255) / 256));
    const float* nf = nullptr;

    // 1) projections (logits / Vp)
    hipLaunchKernelGGL(gemm_f32, gP, blk, 0, stream, SS, DD, DD, q, PB, Wq, 0L, QP, PB, nf, 0L, bq, 1.0f, 0.0f);
    hipLaunchKernelGGL(gemm_f32, gP, blk, 0, stream, SS, DD, DD, k, PB, Wk, 0L, KP, PB, nf, 0L, bk, 1.0f, 0.0f);
    hipLaunchKernelGGL(gemm_f32, gP, blk, 0, stream, SS, DD, DD, v, PB, Wv, 0L, VP, PB, nf, 0L, bv, 1.0f, 0.0f);

    // 2) row softmax (Qp, Kp)
    hipLaunchKernelGGL(softmax_rows, dim3(NB * SS / 4), blk, 0, stream, QP);
    hipLaunchKernelGGL(softmax_rows, dim3(NB * SS / 4), blk, 0, stream, KP);

    // 3) G = Kp^T Kp, M = Kp^T (Kp*Vp)
    hipLaunchKernelGGL(gram_gm, gG, blk, 0, stream, KP, VP, G, Mm);

    // 4) lamMax, tau
    hipLaunchKernelGGL(power_iter, dim3(NB), blk, 0, stream, G, scal);

    // 5) S = sign(G - tau I): 20 aggressive cubics (2.4x - 2.048x^3) + 8 polish (1.5x - 0.5x^3)
    hipLaunchKernelGGL(mat_sign_init, gE, blk, 0, stream, G, X, scal);
    float* sp = X; float* op = T2;
    for (int it = 0; it < 28; ++it) {
        const float a  = (it < 20) ? 2.4f   : 1.5f;
        const float bb = (it < 20) ? 2.048f : 0.5f;
        // T1 = sp*sp ; op = a*sp - bb*(sp*T1)
        hipLaunchKernelGGL(gemm_f32, gG, blk, 0, stream, DD, DD, DD, sp, GB, sp, GB, T1, GB, nf, 0L, nf, 1.0f, 0.0f);
        hipLaunchKernelGGL(gemm_f32, gG, blk, 0, stream, DD, DD, DD, sp, GB, T1, GB, op, GB, sp, GB, nf, -bb, a);
        float* t = sp; sp = op; op = t;
    }

    // 6) truncated inverse: X0 = (S+I)/(2*lamMax); 14 Newton steps X <- 2X - X G X
    hipLaunchKernelGGL(mat_proj_init, gE, blk, 0, stream, sp, op, scal);
    { float* t = sp; sp = op; op = t; }
    for (int it = 0; it < 14; ++it) {
        hipLaunchKernelGGL(gemm_f32, gG, blk, 0, stream, DD, DD, DD, G, GB, sp, GB, T1, GB, nf, 0L, nf, 1.0f, 0.0f);
        hipLaunchKernelGGL(gemm_f32, gG, blk, 0, stream, DD, DD, DD, sp, GB, T1, GB, op, GB, sp, GB, nf, -1.0f, 2.0f);
        float* t = sp; sp = op; op = t;
    }

    // 7) out = Qp * (h(G) * M)
    hipLaunchKernelGGL(gemm_f32, gG, blk, 0, stream, DD, DD, DD, sp, GB, Mm, GB, T1, GB, nf, 0L, nf, 1.0f, 0.0f);
    hipLaunchKernelGGL(gemm_f32, gP, blk, 0, stream, SS, DD, DD, QP, PB, T1, GB, out, PB, nf, 0L, nf, 1.0f, 0.0f);
}

// Round 8
// 6321.687 us; speedup vs baseline: 1.1807x; 1.1807x over previous
//
#include <hip/hip_runtime.h>
#include <cstdint>

// NystromAttention, B=4, S=1024, D=768, m=S (identity pooling).
// out = Qp * h(G) * M,  G = Kp^T Kp,  M = Kp^T (Kp*Vp),
// h(lam) = (1/lam) * 1[lam >= tau],  tau = rtol*lamMax, rtol = 10*1024*eps = 1.220703125e-3
// GEMM-only h(G): Newton-Schulz sign(G - tau I) (20 aggressive cubic + 4 quintic polish)
// -> projector -> seeded Newton inverse (13 iters, seed (S+I)/(lamMax*(1+rtol))).
// GEMM: 128x128 tile, 8x8/thread, BK=16; iteration GEMMs use split-K=4 + reduce kernel
// (576 blocks vs 144 -> ~75% CU util vs 56%) when ws_size permits.

#define NB 4
#define SS 1024
#define DD 768
#define BK 16

static const long PB   = (long)SS * DD;     // per-batch [S,D] stride (floats)
static const long GB   = (long)DD * DD;     // per-batch [D,D] stride
static const long SZ_P = (long)NB * PB;
static const long SZ_G = (long)NB * GB;
#define RTOL 1.220703125e-3f

// ---------------------------------------------------------------------------
// GEMM 128x128 tile, 256 threads, 8x8 per thread, BK=16.
// TA=false: A is [M,K] row-major.  TA=true: A stored [K,M] row-major (logical A^T).
// SPLITK=true: z = (batch<<nsplitLg)|split, each split covers K/nsplit, writes raw
//              partials to C + split*partStride + batch*sC (no epilogue).
// SPLITK=false: full epilogue C = alpha*(A*B) + beta*Dm + bias.
// ---------------------------------------------------------------------------
template<bool TA, bool SPLITK>
__global__ __launch_bounds__(256, 3)
void gemm8(int M, int N, int K, int nsplitLg,
           const float* __restrict__ A, long sA,
           const float* __restrict__ B, long sB,
           float* __restrict__ C, long sC, long partStride,
           const float* __restrict__ Dm, long sD,
           const float* __restrict__ bias,
           float alpha, float beta)
{
    const int z   = blockIdx.z;
    const int bb  = z >> nsplitLg;
    const int sp  = z & ((1 << nsplitLg) - 1);
    const int Ks  = K >> nsplitLg;
    const int kbeg = sp * Ks;

    const float* Ab = A + (long)bb * sA;
    const float* Bb = B + (long)bb * sB;

    __shared__ float As[BK][132];   // [k][row], +4 pad
    __shared__ float Bs[BK][132];   // [k][col]

    const int t  = threadIdx.x;
    const int tx = t & 15, ty = t >> 4;
    const int row0 = blockIdx.y * 128, col0 = blockIdx.x * 128;

    const int a_row = t >> 1;
    const int a_kq  = (t & 1) << 3;
    const int l_k   = t >> 5;          // 0..7
    const int l_q   = (t & 31) << 2;   // 0..124

    float acc[8][8] = {};

    for (int k0 = kbeg; k0 < kbeg + Ks; k0 += BK) {
        if (TA) {
            // A stored [K, M]: row length == M
            float4 v0 = *(const float4*)(Ab + (long)(k0 + l_k) * M + row0 + l_q);
            float4 v1 = *(const float4*)(Ab + (long)(k0 + l_k + 8) * M + row0 + l_q);
            *(float4*)(&As[l_k][l_q])     = v0;
            *(float4*)(&As[l_k + 8][l_q]) = v1;
        } else {
            float4 v0 = *(const float4*)(Ab + (long)(row0 + a_row) * K + k0 + a_kq);
            float4 v1 = *(const float4*)(Ab + (long)(row0 + a_row) * K + k0 + a_kq + 4);
            As[a_kq + 0][a_row] = v0.x; As[a_kq + 1][a_row] = v0.y;
            As[a_kq + 2][a_row] = v0.z; As[a_kq + 3][a_row] = v0.w;
            As[a_kq + 4][a_row] = v1.x; As[a_kq + 5][a_row] = v1.y;
            As[a_kq + 6][a_row] = v1.z; As[a_kq + 7][a_row] = v1.w;
        }
        {
            float4 v0 = *(const float4*)(Bb + (long)(k0 + l_k) * N + col0 + l_q);
            float4 v1 = *(const float4*)(Bb + (long)(k0 + l_k + 8) * N + col0 + l_q);
            *(float4*)(&Bs[l_k][l_q])     = v0;
            *(float4*)(&Bs[l_k + 8][l_q]) = v1;
        }
        __syncthreads();
#pragma unroll
        for (int kk = 0; kk < BK; ++kk) {
            float4 a0 = *(const float4*)(&As[kk][ty << 3]);
            float4 a1 = *(const float4*)(&As[kk][(ty << 3) + 4]);
            float4 b0 = *(const float4*)(&Bs[kk][tx << 3]);
            float4 b1 = *(const float4*)(&Bs[kk][(tx << 3) + 4]);
            float ar[8] = {a0.x,a0.y,a0.z,a0.w,a1.x,a1.y,a1.z,a1.w};
            float br[8] = {b0.x,b0.y,b0.z,b0.w,b1.x,b1.y,b1.z,b1.w};
#pragma unroll
            for (int i = 0; i < 8; ++i)
#pragma unroll
                for (int j = 0; j < 8; ++j)
                    acc[i][j] = fmaf(ar[i], br[j], acc[i][j]);
        }
        __syncthreads();
    }

    if (SPLITK) {
        float* P = C + (long)sp * partStride + (long)bb * sC;
#pragma unroll
        for (int i = 0; i < 8; ++i) {
            const long ro = (long)(row0 + (ty << 3) + i) * N + col0 + (tx << 3);
            *(float4*)(P + ro)     = make_float4(acc[i][0], acc[i][1], acc[i][2], acc[i][3]);
            *(float4*)(P + ro + 4) = make_float4(acc[i][4], acc[i][5], acc[i][6], acc[i][7]);
        }
    } else {
        float* Cb = C + (long)bb * sC;
        const float* Db = Dm ? Dm + (long)bb * sD : nullptr;
#pragma unroll
        for (int i = 0; i < 8; ++i) {
            const int r = row0 + (ty << 3) + i;
            const long ro = (long)r * N + col0 + (tx << 3);
            float4 o0 = make_float4(alpha*acc[i][0], alpha*acc[i][1], alpha*acc[i][2], alpha*acc[i][3]);
            float4 o1 = make_float4(alpha*acc[i][4], alpha*acc[i][5], alpha*acc[i][6], alpha*acc[i][7]);
            if (Db) {
                float4 d0 = *(const float4*)(Db + ro);
                float4 d1 = *(const float4*)(Db + ro + 4);
                o0.x += beta*d0.x; o0.y += beta*d0.y; o0.z += beta*d0.z; o0.w += beta*d0.w;
                o1.x += beta*d1.x; o1.y += beta*d1.y; o1.z += beta*d1.z; o1.w += beta*d1.w;
            }
            if (bias) {
                float4 s0 = *(const float4*)(bias + col0 + (tx << 3));
                float4 s1 = *(const float4*)(bias + col0 + (tx << 3) + 4);
                o0.x += s0.x; o0.y += s0.y; o0.z += s0.z; o0.w += s0.w;
                o1.x += s1.x; o1.y += s1.y; o1.z += s1.z; o1.w += s1.w;
            }
            *(float4*)(Cb + ro)     = o0;
            *(float4*)(Cb + ro + 4) = o1;
        }
    }
}

// out = alpha * sum_p parts[p] + beta * Dm   (flat over NB*GB, float4-vectorized)
__global__ __launch_bounds__(256)
void reduceN(const float* __restrict__ P, long partStride, int nparts,
             float* __restrict__ C, const float* __restrict__ Dm,
             float alpha, float beta, long n4)
{
    const long i = (long)blockIdx.x * 256 + threadIdx.x;
    if (i >= n4) return;
    float4 s = ((const float4*)P)[i];
    for (int p = 1; p < nparts; ++p) {
        float4 v = ((const float4*)(P + (long)p * partStride))[i];
        s.x += v.x; s.y += v.y; s.z += v.z; s.w += v.w;
    }
    float4 o = make_float4(alpha*s.x, alpha*s.y, alpha*s.z, alpha*s.w);
    if (Dm) {
        float4 d = ((const float4*)Dm)[i];
        o.x += beta*d.x; o.y += beta*d.y; o.z += beta*d.z; o.w += beta*d.w;
    }
    ((float4*)C)[i] = o;
}

// ---------------------------------------------------------------------------
// Row softmax over D=768. One wave per row, 4 waves per block.
// ---------------------------------------------------------------------------
__global__ __launch_bounds__(256)
void softmax_rows(float* __restrict__ P)
{
    const int row  = blockIdx.x * 4 + (threadIdx.x >> 6);
    const int lane = threadIdx.x & 63;
    float* rp = P + (long)row * DD;
    float v[12];
    float mx = -3.4e38f;
#pragma unroll
    for (int i = 0; i < 12; ++i) { v[i] = rp[lane + (i << 6)]; mx = fmaxf(mx, v[i]); }
#pragma unroll
    for (int off = 32; off > 0; off >>= 1) mx = fmaxf(mx, __shfl_xor(mx, off, 64));
    float sum = 0.f;
#pragma unroll
    for (int i = 0; i < 12; ++i) { v[i] = expf(v[i] - mx); sum += v[i]; }
#pragma unroll
    for (int off = 32; off > 0; off >>= 1) sum += __shfl_xor(sum, off, 64);
#pragma unroll
    for (int i = 0; i < 12; ++i) rp[lane + (i << 6)] = v[i] / sum;
}

// VP *= KP elementwise (forms Kp*Vp in place)
__global__ __launch_bounds__(256)
void kv_mul(const float* __restrict__ KP, float* __restrict__ VP)
{
    const long i = (long)blockIdx.x * 256 + threadIdx.x;
    if (i < SZ_P) VP[i] *= KP[i];
}

// ---------------------------------------------------------------------------
// Power iteration (unnormalized, ping-pong matvecs). One wave per row.
// ---------------------------------------------------------------------------
__global__ __launch_bounds__(256)
void init_ones(float* __restrict__ v)
{
    const int i = blockIdx.x * 256 + threadIdx.x;
    if (i < NB * DD) v[i] = 1.0f;
}

__global__ __launch_bounds__(256)
void mv768(const float* __restrict__ G, const float* __restrict__ vin,
           float* __restrict__ vout)
{
    const int b = blockIdx.y;
    const int r = blockIdx.x * 4 + (threadIdx.x >> 6);
    const int l = threadIdx.x & 63;
    const float* Gr = G + (long)b * GB + (long)r * DD;
    const float* vb = vin + b * DD;
    float s = 0.f;
#pragma unroll
    for (int j = 0; j < 3; ++j) {
        float4 g4 = *(const float4*)(Gr + (l << 2) + j * 256);
        float4 v4 = *(const float4*)(vb + (l << 2) + j * 256);
        s = fmaf(g4.x, v4.x, s); s = fmaf(g4.y, v4.y, s);
        s = fmaf(g4.z, v4.z, s); s = fmaf(g4.w, v4.w, s);
    }
#pragma unroll
    for (int off = 32; off > 0; off >>= 1) s += __shfl_xor(s, off, 64);
    if (l == 0) vout[b * DD + r] = s;
}

// lam = ||v_cur|| / ||v_prev|| per batch; writes scal[16]
__global__ __launch_bounds__(256)
void lam_tau(const float* __restrict__ vprev, const float* __restrict__ vcur,
             float* __restrict__ scal)
{
    __shared__ float red[256];
    const int t = threadIdx.x;
    for (int b = 0; b < NB; ++b) {
        float sp = 0.f, sc = 0.f;
        for (int i = t; i < DD; i += 256) {
            float a = vprev[b * DD + i], c = vcur[b * DD + i];
            sp = fmaf(a, a, sp); sc = fmaf(c, c, sc);
        }
        red[t] = sp; __syncthreads();
        for (int o = 128; o > 0; o >>= 1) { if (t < o) red[t] += red[t + o]; __syncthreads(); }
        const float np = red[0]; __syncthreads();
        red[t] = sc; __syncthreads();
        for (int o = 128; o > 0; o >>= 1) { if (t < o) red[t] += red[t + o]; __syncthreads(); }
        const float nc = red[0]; __syncthreads();
        if (t == 0) {
            const float lam = sqrtf(nc / np);
            scal[b]      = lam;
            scal[4 + b]  = RTOL * lam;
            scal[8 + b]  = 1.0f / lam;
            scal[12 + b] = 1.0f / (lam * (1.0f + RTOL));
        }
        __syncthreads();
    }
}

// X = (G - tau*I) / lamMax
__global__ __launch_bounds__(256)
void mat_sign_init(const float* __restrict__ G, float* __restrict__ X,
                   const float* __restrict__ scal)
{
    const long idx = (long)blockIdx.x * 256 + threadIdx.x;
    if (idx >= SZ_G) return;
    const int b = (int)(idx / GB);
    const long rem = idx % GB;
    const int r = (int)(rem / DD), c = (int)(rem % DD);
    float g = G[idx];
    if (r == c) g -= scal[4 + b];
    X[idx] = g * scal[8 + b];
}

// X0 = (S + I) / (lamMax*(1+rtol))
__global__ __launch_bounds__(256)
void mat_proj_init(const float* __restrict__ Sg, float* __restrict__ X,
                   const float* __restrict__ scal)
{
    const long idx = (long)blockIdx.x * 256 + threadIdx.x;
    if (idx >= SZ_G) return;
    const int b = (int)(idx / GB);
    const long rem = idx % GB;
    const int r = (int)(rem / DD), c = (int)(rem % DD);
    float s = Sg[idx];
    if (r == c) s += 1.0f;
    X[idx] = s * scal[12 + b];
}

// U = 1.875*I - 1.25*T + 0.375*T2   (quintic sign polish; U may alias T)
__global__ __launch_bounds__(256)
void quintic_u(const float* __restrict__ T, const float* __restrict__ T2,
               float* __restrict__ U)
{
    const long idx = (long)blockIdx.x * 256 + threadIdx.x;
    if (idx >= SZ_G) return;
    const long rem = idx % GB;
    const int r = (int)(rem / DD), c = (int)(rem % DD);
    float u = -1.25f * T[idx] + 0.375f * T2[idx];
    if (r == c) u += 1.875f;
    U[idx] = u;
}

// ---------------------------------------------------------------------------
extern "C" void kernel_launch(void* const* d_in, const int* in_sizes, int n_in,
                              void* d_out, int out_size, void* d_ws, size_t ws_size,
                              hipStream_t stream)
{
    (void)in_sizes; (void)n_in; (void)out_size;
    const float* q  = (const float*)d_in[0];
    const float* k  = (const float*)d_in[1];
    const float* v  = (const float*)d_in[2];
    const float* Wq = (const float*)d_in[3];
    const float* bq = (const float*)d_in[4];
    const float* Wk = (const float*)d_in[5];
    const float* bk = (const float*)d_in[6];
    const float* Wv = (const float*)d_in[7];
    const float* bv = (const float*)d_in[8];
    float* out = (float*)d_out;

    float* ws = (float*)d_ws;
    float* QP    = ws;                    // [B,S,D]
    float* KP    = QP + SZ_P;             // [B,S,D] -> reused as sign/Newton buffer
    float* VP    = KP + SZ_P;             // [B,S,D] (becomes Kp*Vp) -> reused as t1
    float* G     = VP + SZ_P;             // [B,D,D]
    float* Mm    = G  + SZ_G;             // [B,D,D]
    float* Yb    = Mm + SZ_G;             // [B,D,D]
    float* Ub    = Yb + SZ_G;             // [B,D,D]
    float* vb0   = Ub + SZ_G;             // [B,768]
    float* vb1   = vb0 + NB * DD;
    float* scal  = vb1 + NB * DD;         // 16
    float* parts = scal + 16;             // [4][B,D,D] (split path only)
    const size_t need_split = (size_t)((parts + 4 * SZ_G) - ws) * sizeof(float);
    const bool split = ws_size >= need_split;

    const dim3 blk(256);
    const dim3 gP(6, 8, NB);              // [1024,768] outputs
    const dim3 gG(6, 6, NB);              // [768,768] outputs
    const dim3 gGs(6, 6, NB * 4);         // split-K=4
    const dim3 gE((unsigned)((SZ_G + 255) / 256));
    const float* nf = nullptr;
    const long n4 = SZ_G / 4;
    const unsigned gR = (unsigned)((n4 + 255) / 256);

    // iteration GEMM on DxD: out = alpha*(A*B) + beta*Dmat
    auto iterGemm = [&](const float* A_, const float* B_, float* out_,
                        const float* Dm_, float alpha_, float beta_) {
        if (split) {
            hipLaunchKernelGGL((gemm8<false, true>), gGs, blk, 0, stream,
                               DD, DD, DD, 2, A_, GB, B_, GB,
                               parts, GB, (long)NB * GB, nf, 0L, nf, 1.0f, 0.0f);
            hipLaunchKernelGGL(reduceN, dim3(gR), blk, 0, stream,
                               parts, (long)NB * GB, 4, out_, Dm_, alpha_, beta_, n4);
        } else {
            hipLaunchKernelGGL((gemm8<false, false>), gG, blk, 0, stream,
                               DD, DD, DD, 0, A_, GB, B_, GB,
                               out_, GB, 0L, Dm_, GB, nf, alpha_, beta_);
        }
    };

    // 1) projections (fp32 GEMM + bias)
    hipLaunchKernelGGL((gemm8<false, false>), gP, blk, 0, stream,
                       SS, DD, DD, 0, q, PB, Wq, 0L, QP, PB, 0L, nf, 0L, bq, 1.0f, 0.0f);
    hipLaunchKernelGGL((gemm8<false, false>), gP, blk, 0, stream,
                       SS, DD, DD, 0, k, PB, Wk, 0L, KP, PB, 0L, nf, 0L, bk, 1.0f, 0.0f);
    hipLaunchKernelGGL((gemm8<false, false>), gP, blk, 0, stream,
                       SS, DD, DD, 0, v, PB, Wv, 0L, VP, PB, 0L, nf, 0L, bv, 1.0f, 0.0f);

    // 2) row softmax (Qp, Kp)
    hipLaunchKernelGGL(softmax_rows, dim3(NB * SS / 4), blk, 0, stream, QP);
    hipLaunchKernelGGL(softmax_rows, dim3(NB * SS / 4), blk, 0, stream, KP);

    // 3) VP = Kp*Vp;  G = Kp^T Kp;  Mm = Kp^T (Kp*Vp)   (transposed-A GEMMs, K=1024)
    hipLaunchKernelGGL(kv_mul, dim3((unsigned)((SZ_P + 255) / 256)), blk, 0, stream, KP, VP);
    hipLaunchKernelGGL((gemm8<true, false>), gG, blk, 0, stream,
                       DD, DD, SS, 0, KP, PB, KP, PB, G, GB, 0L, nf, 0L, nf, 1.0f, 0.0f);
    hipLaunchKernelGGL((gemm8<true, false>), gG, blk, 0, stream,
                       DD, DD, SS, 0, KP, PB, VP, PB, Mm, GB, 0L, nf, 0L, nf, 1.0f, 0.0f);

    // 4) lamMax via 8 unnormalized power-iteration matvecs (parallel across 3072 rows)
    hipLaunchKernelGGL(init_ones, dim3(12), blk, 0, stream, vb0);
    for (int it = 0; it < 4; ++it) {
        hipLaunchKernelGGL(mv768, dim3(192, NB), blk, 0, stream, G, vb0, vb1);
        hipLaunchKernelGGL(mv768, dim3(192, NB), blk, 0, stream, G, vb1, vb0);
    }
    // after 8 matvecs: prev = vb1 (7th), cur = vb0 (8th)
    hipLaunchKernelGGL(lam_tau, dim3(1), blk, 0, stream, vb1, vb0, scal);

    // 5) sign(G - tau I): 20 aggressive cubics f(x)=2.4x-2.048x^3
    //    then 4 quintic polish p(x)=(15x-10x^3+3x^5)/8
    float* cur = KP;   // sign/Newton ping-pong buffers
    float* oth = Yb;
    float* t1  = VP;
    float* t2  = Ub;
    hipLaunchKernelGGL(mat_sign_init, gE, blk, 0, stream, G, cur, scal);
    for (int it = 0; it < 20; ++it) {
        iterGemm(cur, cur, t1, nf, 1.0f, 0.0f);            // t1 = X^2
        iterGemm(cur, t1, oth, cur, -2.048f, 2.4f);        // Y = 2.4X - 2.048 X*t1
        float* tmp = cur; cur = oth; oth = tmp;
    }
    for (int it = 0; it < 4; ++it) {
        iterGemm(cur, cur, t1, nf, 1.0f, 0.0f);            // t1 = X^2
        iterGemm(t1, t1, t2, nf, 1.0f, 0.0f);              // t2 = X^4
        hipLaunchKernelGGL(quintic_u, gE, blk, 0, stream, t1, t2, t1); // t1 = 1.875I-1.25T+0.375T^2
        iterGemm(cur, t1, oth, nf, 1.0f, 0.0f);            // Y = X * U
        float* tmp = cur; cur = oth; oth = tmp;
    }

    // 6) truncated inverse: X0 = (S+I)/(lamMax*(1+rtol)); 13 Newton steps X <- 2X - X G X
    hipLaunchKernelGGL(mat_proj_init, gE, blk, 0, stream, cur, oth, scal);
    { float* tmp = cur; cur = oth; oth = tmp; }
    for (int it = 0; it < 13; ++it) {
        iterGemm(G, cur, t1, nf, 1.0f, 0.0f);              // t1 = G X
        iterGemm(cur, t1, oth, cur, -1.0f, 2.0f);          // Y = 2X - X t1
        float* tmp = cur; cur = oth; oth = tmp;
    }

    // 7) out = Qp * (h(G) * Mm)
    hipLaunchKernelGGL((gemm8<false, false>), gG, blk, 0, stream,
                       DD, DD, DD, 0, cur, GB, Mm, GB, t1, GB, 0L, nf, 0L, nf, 1.0f, 0.0f);
    hipLaunchKernelGGL((gemm8<false, false>), gP, blk, 0, stream,
                       SS, DD, DD, 0, QP, PB, t1, GB, out, PB, 0L, nf, 0L, nf, 1.0f, 0.0f);
}